// Round 16
// baseline (504.174 us; speedup 1.0000x reference)
//
#include <hip/hip_runtime.h>
#include <hip/hip_bf16.h>

static constexpr int LL = 256;   // sequence length / nodes
static constexpr int BB = 128;   // batch
static constexpr int HHH = 512;  // hidden dim

typedef __attribute__((ext_vector_type(8))) short bf16x8;
typedef __attribute__((ext_vector_type(4))) float f32x4;
typedef __attribute__((ext_vector_type(8))) unsigned short u16x8;
typedef __attribute__((ext_vector_type(4))) unsigned short u16x4;

__device__ __forceinline__ unsigned short f2bf(float f) {
  union { float f; unsigned u; } v; v.f = f;
  unsigned r = (v.u + 0x7FFFu + ((v.u >> 16) & 1u)) >> 16;
  return (unsigned short)r;
}
__device__ __forceinline__ float bf2f(unsigned short s) {
  union { unsigned u; float f; } v; v.u = ((unsigned)s) << 16;
  return v.f;
}
__device__ __forceinline__ float sigm(float x) { return 1.0f / (1.0f + __expf(-x)); }
__device__ __forceinline__ float tanh_f(float x) { return 1.0f - 2.0f / (__expf(2.0f * x) + 1.0f); }

// ---------------------------------------------------------------------------
// Kernel 1: prep (round-14/15 verbatim).
//   0..1023   : cast 4 x-weight matrices -> Wxbf (bf16 row-major)
//   1024..1535: pack 4 h-weight matrices -> Whp (MFMA B-fragment order)
//   1536..1792: zero flag8[32768] (u64 each) (+tick in 1536)
// ---------------------------------------------------------------------------
__global__ __launch_bounds__(256) void prep(
    const float* __restrict__ s0, const float* __restrict__ s1,
    const float* __restrict__ s2, const float* __restrict__ s3,
    const float* __restrict__ h0, const float* __restrict__ h1,
    const float* __restrict__ h2, const float* __restrict__ h3,
    unsigned short* __restrict__ wx, unsigned short* __restrict__ whp,
    int* __restrict__ flag8i, int* __restrict__ tick) {
  const int blk = blockIdx.x;
  const int tid = threadIdx.x;
  if (blk < 1024) {
    int gid = blk * 256 + tid;
    int e = gid * 4;
    int m = e >> 18;
    int off = e & 0x3FFFF;
    const float* srcs[4] = {s0, s1, s2, s3};
    float4 v = *(const float4*)(srcs[m] + off);
    u16x4 o;
    o[0] = f2bf(v.x); o[1] = f2bf(v.y); o[2] = f2bf(v.z); o[3] = f2bf(v.w);
    *(u16x4*)(wx + (size_t)m * 262144 + off) = o;
  } else if (blk < 1536) {
    int gid = (blk - 1024) * 256 + tid;
    int lane = gid & 63;
    int kb   = (gid >> 6) & 15;
    int n16  = (gid >> 10) & 31;
    int g    = gid >> 15;
    const float* W = (g == 0) ? h0 : (g == 1) ? h1 : (g == 2) ? h2 : h3;
    int row = n16 * 16 + (lane & 15);
    int col = kb * 32 + (lane >> 4) * 8;
    const float4* s = (const float4*)(W + (size_t)row * 512 + col);
    float4 v0 = s[0], v1 = s[1];
    u16x8 o;
    o[0] = f2bf(v0.x); o[1] = f2bf(v0.y); o[2] = f2bf(v0.z); o[3] = f2bf(v0.w);
    o[4] = f2bf(v1.x); o[5] = f2bf(v1.y); o[6] = f2bf(v1.z); o[7] = f2bf(v1.w);
    *(u16x8*)&whp[(size_t)gid * 8] = o;
  } else {
    int i = (blk - 1536) * 256 + tid;
    if (i < 65536) flag8i[i] = 0;
    if (blk == 1536 && tid < 9) tick[tid] = 0;
  }
}

// ---------------------------------------------------------------------------
// Kernel 2: xproj + levels.  ONE change vs round 15: 512-thread / 8-wave
// blocks (wave w -> rows wr=w&3 (32 each), cols wc=w>>2 (64 each)) so each
// wave holds only acc[2][4] (32 AGPR) -> ~112 unified regs/wave -> 4 waves/
// SIMD, 2 blocks/CU = 16 waves/CU (vs 5).  Staging/epilogue re-indexed for
// 512 threads; T1 XCD-chunked swizzle and LDS-staged coalesced writes kept.
//   block 0      : level assignment + bucketing + tile list.
//   blocks 1..4096: one 128x128 tile of Xpre = cvt_bf16(X) @ Wx^T + bias.
// ---------------------------------------------------------------------------
__global__ __launch_bounds__(512) void xprojL(
    const float* __restrict__ X, const unsigned short* __restrict__ Wx,
    const float* __restrict__ bi_x, const float* __restrict__ bi_h,
    const float* __restrict__ bf_x, const float* __restrict__ bf_h,
    unsigned short* __restrict__ Xpre,
    const int* __restrict__ parents, int* __restrict__ pairs,
    int* __restrict__ lmeta, int* __restrict__ mrows) {
  __shared__ union {
    unsigned short sh[2][8192];                 // 32 KB GEMM staging
    struct {
      unsigned short cnt2[128][130];            // 33.3 KB
      int off[130];
      int maxl;
    } lv;
  } U;
  const int tid = threadIdx.x;

  if (blockIdx.x == 0) {
    // ---- levels role (threads 0..127 carry state; all 512 hit barriers) --
    const int b = tid;
    unsigned char mylvl[256];
    if (b < 128) {
      for (int l = 0; l < 130; ++l) U.lv.cnt2[b][l] = 0;
    }
    if (b == 0) U.lv.maxl = 0;
    __syncthreads();
    if (b < 128) {
      int maxl = 0;
      for (int t = 0; t < 256; ++t) {
        int p = parents[t * 128 + b];
        int l = (p < 0) ? 0 : (mylvl[p] + 1);
        if (l > 127) l = 127;
        mylvl[t] = (unsigned char)l;
        maxl = l > maxl ? l : maxl;
        U.lv.cnt2[b][l]++;
      }
      atomicMax(&U.lv.maxl, maxl);
    }
    __syncthreads();
    const int nlev = U.lv.maxl + 1;
    if (b < 128) {
      int l = b;
      int s = 0;
      if (l < nlev) for (int bb = 0; bb < 128; ++bb) s += U.lv.cnt2[bb][l];
      U.lv.off[l + 1] = s;
    }
    __syncthreads();
    if (b == 0) {
      U.lv.off[0] = 0;
      for (int l = 0; l < 128; ++l) U.lv.off[l + 1] += U.lv.off[l];
    }
    __syncthreads();
    if (b < 128) {
      int l = b;
      if (l < nlev) {
        int run = U.lv.off[l];
        for (int bb = 0; bb < 128; ++bb) {
          int c = U.lv.cnt2[bb][l];
          U.lv.cnt2[bb][l] = (unsigned short)run;
          run += c;
        }
      }
    }
    __syncthreads();
    if (b < 128) {
      for (int t = 0; t < 256; ++t) {
        int l = mylvl[t];
        int pos = U.lv.cnt2[b][l]++;
        pairs[pos] = t * 128 + b;
      }
    }
    if (b == 0) {
      int midx = 0;
      for (int l = 0; l < nlev; ++l) {
        int s = U.lv.off[l], e = U.lv.off[l + 1];
        for (int rb = s; rb < e; rb += 32) {
          int rc = (e - rb < 32) ? (e - rb) : 32;
          mrows[midx++] = (rb << 6) | rc;
        }
      }
      lmeta[0] = midx;
    }
    return;
  }

  // ---- xproj role: 8 waves, wave w -> 32 rows x 64 cols ----
  const int d = blockIdx.x - 1;                 // dispatch index 0..4095
  const int xblk = (d & 7) * 512 + (d >> 3);    // XCD-chunked swizzle (T1)
  const int m0 = (xblk >> 4) * 128;
  const int n0 = (xblk & 15) * 128;
  const int lane = tid & 63, w = tid >> 6;
  const int wr = w & 3, wc = w >> 2;
  const int hi = lane >> 4, l15 = lane & 15;
  f32x4 acc[2][4] = {};
  for (int kt = 0; kt < 8; ++kt) {
    const int k0 = kt * 64;
    __syncthreads();
    // B: async gload_lds, linear dest, inverse-swizzled global source
#pragma unroll
    for (int i = 0; i < 2; ++i) {
      const int grp = i * 8 + w;               // 0..15
      const int unit = grp * 64 + lane;        // 0..1023
      const int row = unit >> 3, c8p = unit & 7;
      const int c8l = c8p ^ (row & 7);
      const unsigned short* gb = Wx + (size_t)(n0 + row) * 512 + k0 + c8l * 8;
      __builtin_amdgcn_global_load_lds(
          (const __attribute__((address_space(1))) unsigned int*)gb,
          (__attribute__((address_space(3))) unsigned int*)(&U.sh[1][grp * 512]),
          16, 0, 0);
    }
    // A: f32 load + cvt + swizzled ds_write_b128
#pragma unroll
    for (int i = 0; i < 2; ++i) {
      const int unit = i * 512 + tid;          // 0..1023
      const int row = unit >> 3, c8l = unit & 7;
      const float* src = X + (size_t)(m0 + row) * 512 + k0 + c8l * 8;
      float4 v0 = ((const float4*)src)[0];
      float4 v1 = ((const float4*)src)[1];
      u16x8 o;
      o[0] = f2bf(v0.x); o[1] = f2bf(v0.y); o[2] = f2bf(v0.z); o[3] = f2bf(v0.w);
      o[4] = f2bf(v1.x); o[5] = f2bf(v1.y); o[6] = f2bf(v1.z); o[7] = f2bf(v1.w);
      *(u16x8*)&U.sh[0][row * 64 + ((c8l ^ (row & 7)) << 3)] = o;
    }
    __syncthreads();
#pragma unroll
    for (int kk = 0; kk < 2; ++kk) {
      const int kofs = kk * 32 + hi * 8;
      bf16x8 a[2], bb[4];
#pragma unroll
      for (int mi = 0; mi < 2; ++mi) {
        const int row = wr * 32 + mi * 16 + l15;
        a[mi] = *(const bf16x8*)&U.sh[0][row * 64 + (kofs ^ ((row & 7) << 3))];
      }
#pragma unroll
      for (int ni = 0; ni < 4; ++ni) {
        const int row = wc * 64 + ni * 16 + l15;
        bb[ni] = *(const bf16x8*)&U.sh[1][row * 64 + (kofs ^ ((row & 7) << 3))];
      }
#pragma unroll
      for (int mi = 0; mi < 2; ++mi)
#pragma unroll
        for (int ni = 0; ni < 4; ++ni)
          acc[mi][ni] = __builtin_amdgcn_mfma_f32_16x16x32_bf16(a[mi], bb[ni], acc[mi][ni], 0, 0, 0);
    }
  }
  // ---- epilogue: stage C in LDS, then coalesced writes ----
  __syncthreads();
  unsigned short* Cs = &U.sh[0][0];   // 128x128 u16 = 32 KB contiguous
#pragma unroll
  for (int ni = 0; ni < 4; ++ni) {
    const int coll = wc * 64 + ni * 16 + l15;
    const int gcol = n0 + coll;
    const int g = gcol >> 9, hh = gcol & 511;
    float badd = 0.0f;
    if (g == 0) badd = bi_x[hh] + bi_h[hh];
    else if (g == 1) badd = bf_x[hh] + bf_h[hh];
#pragma unroll
    for (int mi = 0; mi < 2; ++mi) {
      const int rbase = wr * 32 + mi * 16 + hi * 4;
#pragma unroll
      for (int q = 0; q < 4; ++q)
        Cs[(rbase + q) * 128 + coll] = f2bf(acc[mi][ni][q] + badd);
    }
  }
  __syncthreads();
#pragma unroll
  for (int u = 0; u < 4; ++u) {
    const int unit = u * 512 + tid;            // 0..2047
    const int row = unit >> 4, c8 = unit & 15;
    *(u16x8*)&Xpre[(size_t)(m0 + row) * 2048 + n0 + c8 * 8] =
        *(const u16x8*)&Cs[row * 128 + c8 * 8];
  }
}

// ---------------------------------------------------------------------------
// Kernel 3: recurrence — round-15 verbatim (flag8 vector release, round-10
// core: VGPR 100 / AGPR-resident weights, per-ct ticket queues, fence-free
// LLC protocol).  Stable at ~275 us across rounds 13-15 (structural floor).
// ---------------------------------------------------------------------------
__global__ __launch_bounds__(512, 2) void treelstm_flag(
    const unsigned short* __restrict__ Xpre,  // [L*B][2048]
    const unsigned short* __restrict__ Whp,   // packed [4][32][16][512]
    const int* __restrict__ parents,          // [L][B]
    const int* __restrict__ pairs,            // [32768] node ids by level
    const int* __restrict__ lmeta,            // [0] = mcnt
    const int* __restrict__ mrows,            // tile list (rbase<<6 | rcnt)
    unsigned long long* __restrict__ flag8,   // [32768] per-node ct bytes
    int* __restrict__ tick,                   // [8] ticket counters
    float* __restrict__ Hout,                 // [B][L][H]  (d_out)
    float* __restrict__ Cbuf,                 // [B][L][H]
    unsigned short* __restrict__ Hbf) {       // [B][L][H] bf16
  __shared__ unsigned short phs[32][536];     // 34.3KB
  __shared__ float gbuf[4][32][66];           // 33.8KB
  __shared__ int sh_ticket;
  const int tid = threadIdx.x;
  const int lane = tid & 63, w = tid >> 6;
  const int g = w & 3, nh = w >> 2;
  const int ct = blockIdx.x & 7;
  const int mcnt = lmeta[0];
  const int hi = lane >> 4, l15 = lane & 15;
  const unsigned long long FULL = 0x0101010101010101ull;

  // ---- preload weights for (gate g, cols ct*64+nh*32 ..+32) into regs ----
  bf16x8 wfrag[2][16];
  {
    const size_t base = (size_t)((g * 32 + ct * 4 + nh * 2) * 16) * 512 + lane * 8;
#pragma unroll
    for (int kb = 0; kb < 16; ++kb) {
      wfrag[0][kb] = *(const bf16x8*)&Whp[base + (size_t)kb * 512];
      wfrag[1][kb] = *(const bf16x8*)&Whp[base + (size_t)(16 + kb) * 512];
    }
  }
  // keep-alive: opaque values -> no rematerialization (AGPR residency).
#pragma unroll
  for (int kb = 0; kb < 16; ++kb) {
    asm volatile("" : "+v"(wfrag[0][kb]));
    asm volatile("" : "+v"(wfrag[1][kb]));
  }

  while (true) {
    __syncthreads();   // protect sh_ticket / phs / gbuf from previous iter
    if (tid == 0) sh_ticket = atomicAdd(&tick[ct], 1);
    __syncthreads();
    const int my = sh_ticket;
    if (my >= mcnt) break;
    const int mr = mrows[my];
    const int rbase = mr >> 6;
    const int rcnt = mr & 63;

    // thread -> (row r = tid>>4, chunk q16 = tid&15)
    const int r = tid >> 4;
    const int q16 = tid & 15;
    const int hc = q16 * 4;
    const int h = ct * 64 + hc;
    int node = 0, p = -1, b = 0;
    if (r < rcnt) {
      node = pairs[rbase + r];
      p = parents[node];
      b = node & 127;
    }
    // prefetch Xpre gate pre-activations (no dependency on parents)
    u16x4 xga[4] = {};
    if (r < rcnt) {
#pragma unroll
      for (int gg = 0; gg < 4; ++gg)
        xga[gg] = *(const u16x4*)(Xpre + (size_t)node * 2048 + gg * 512 + h);
    }

    // ---- phase A: wave-0 lanes poll readiness (relaxed u64 loads) ----
    if (tid < 32) {
      int pn = -1;
      if (tid < rcnt) {
        const int node2 = pairs[rbase + tid];
        const int p2 = parents[node2];
        if (p2 >= 0) pn = p2 * 128 + (node2 & 127);
      }
      if (pn >= 0) {
        while (__hip_atomic_load(&flag8[pn], __ATOMIC_RELAXED,
                                 __HIP_MEMORY_SCOPE_AGENT) != FULL)
          __builtin_amdgcn_s_sleep(1);
      }
    }
    __syncthreads();

    // ---- phase B: prefetch parent c; gather parent h rows into LDS ----
    float4 pc = make_float4(0.f, 0.f, 0.f, 0.f);
    if (r < rcnt && p >= 0)
      pc = *(const float4*)(Cbuf + ((size_t)b * LL + p) * HHH + h);
    if (p >= 0) {
      const unsigned short* src = Hbf + ((size_t)b * LL + p) * HHH + q16 * 32;
#pragma unroll
      for (int j = 0; j < 4; ++j)
        *(u16x8*)&phs[r][q16 * 32 + j * 8] = ((const u16x8*)src)[j];
    } else {
      u16x8 z = {};
#pragma unroll
      for (int j = 0; j < 4; ++j) *(u16x8*)&phs[r][q16 * 32 + j * 8] = z;
    }
    __syncthreads();

    // ---- phase C: wave (g, nh): 32 rows x 32 cols, K=512 ----
    f32x4 acc[2][2] = {};
#pragma unroll
    for (int kb = 0; kb < 16; ++kb) {
      const int ko = kb * 32 + 8 * hi;
      bf16x8 a0 = *(const bf16x8*)&phs[l15][ko];
      bf16x8 a1 = *(const bf16x8*)&phs[16 + l15][ko];
      acc[0][0] = __builtin_amdgcn_mfma_f32_16x16x32_bf16(a0, wfrag[0][kb], acc[0][0], 0, 0, 0);
      acc[1][0] = __builtin_amdgcn_mfma_f32_16x16x32_bf16(a1, wfrag[0][kb], acc[1][0], 0, 0, 0);
      acc[0][1] = __builtin_amdgcn_mfma_f32_16x16x32_bf16(a0, wfrag[1][kb], acc[0][1], 0, 0, 0);
      acc[1][1] = __builtin_amdgcn_mfma_f32_16x16x32_bf16(a1, wfrag[1][kb], acc[1][1], 0, 0, 0);
    }
#pragma unroll
    for (int mi = 0; mi < 2; ++mi)
#pragma unroll
      for (int ni = 0; ni < 2; ++ni)
#pragma unroll
        for (int qq = 0; qq < 4; ++qq)
          gbuf[g][mi * 16 + hi * 4 + qq][nh * 32 + ni * 16 + l15] = acc[mi][ni][qq];
    __syncthreads();

    // ---- phase D: elementwise gates ----
    float hva[4];
    size_t obase = 0;
    const bool valid = (r < rcnt);
    if (valid) {
      const int t = node >> 7;
      float xg[4][4];
#pragma unroll
      for (int gg = 0; gg < 4; ++gg)
#pragma unroll
        for (int j = 0; j < 4; ++j) xg[gg][j] = bf2f(xga[gg][j]);
      const float pcv[4] = {pc.x, pc.y, pc.z, pc.w};
      float cva[4];
#pragma unroll
      for (int j = 0; j < 4; ++j) {
        float iv = sigm(gbuf[0][r][hc + j] + xg[0][j]);
        float fv = sigm(gbuf[1][r][hc + j] + xg[1][j]);
        float ov = sigm(gbuf[2][r][hc + j] + xg[2][j]);
        float uv = tanh_f(gbuf[3][r][hc + j] + xg[3][j]);
        float cv = iv * uv + fv * pcv[j];
        cva[j] = cv;
        hva[j] = ov * tanh_f(cv);
      }
      obase = ((size_t)b * LL + t) * HHH + h;
      // Cbuf, Hbf: consumed by other WGs -> write through to LLC (sc1)
      union { float f[4]; unsigned long long u[2]; } cvu;
      cvu.f[0] = cva[0]; cvu.f[1] = cva[1]; cvu.f[2] = cva[2]; cvu.f[3] = cva[3];
      unsigned long long* cp = (unsigned long long*)(Cbuf + obase);
      __hip_atomic_store(cp, cvu.u[0], __ATOMIC_RELAXED, __HIP_MEMORY_SCOPE_AGENT);
      __hip_atomic_store(cp + 1, cvu.u[1], __ATOMIC_RELAXED, __HIP_MEMORY_SCOPE_AGENT);
      union { unsigned short s[4]; unsigned long long u; } hbu;
      hbu.s[0] = f2bf(hva[0]); hbu.s[1] = f2bf(hva[1]);
      hbu.s[2] = f2bf(hva[2]); hbu.s[3] = f2bf(hva[3]);
      __hip_atomic_store((unsigned long long*)(Hbf + obase), hbu.u,
                         __ATOMIC_RELAXED, __HIP_MEMORY_SCOPE_AGENT);
    }
    // drain this wave's LLC stores (row's 16 threads all in this wave)
    asm volatile("s_waitcnt vmcnt(0)" ::: "memory");
    if (valid && q16 == 0) {
      unsigned char* fb = (unsigned char*)flag8 + ((size_t)node * 8 + ct);
      __hip_atomic_store(fb, (unsigned char)1, __ATOMIC_RELAXED,
                         __HIP_MEMORY_SCOPE_AGENT);
    }
    // Hout (pure output, HBM) after the release -> off the critical path
    if (valid)
      *(float4*)(Hout + obase) = make_float4(hva[0], hva[1], hva[2], hva[3]);
  }
}

// ---------------------------------------------------------------------------
extern "C" void kernel_launch(void* const* d_in, const int* in_sizes, int n_in,
                              void* d_out, int out_size, void* d_ws, size_t ws_size,
                              hipStream_t stream) {
  const float* X    = (const float*)d_in[0];
  const float* Wi_x = (const float*)d_in[1];
  const float* bi_x = (const float*)d_in[2];
  const float* Wi_h = (const float*)d_in[3];
  const float* bi_h = (const float*)d_in[4];
  const float* Wf_x = (const float*)d_in[5];
  const float* bf_x = (const float*)d_in[6];
  const float* Wf_h = (const float*)d_in[7];
  const float* bf_h = (const float*)d_in[8];
  const float* Wo_x = (const float*)d_in[9];
  const float* Wo_h = (const float*)d_in[10];
  const float* Wu_x = (const float*)d_in[11];
  const float* Wu_h = (const float*)d_in[12];
  const int* parents = (const int*)d_in[13];
  float* Hout = (float*)d_out;

  char* ws = (char*)d_ws;
  unsigned short* Xpre = (unsigned short*)ws; ws += (size_t)32768 * 2048 * 2;  // 128 MB
  unsigned short* Hbf  = (unsigned short*)ws; ws += (size_t)BB * LL * HHH * 2; // 32 MB
  float*          Cbuf = (float*)ws;          ws += (size_t)BB * LL * HHH * 4; // 64 MB
  unsigned short* Wxbf = (unsigned short*)ws; ws += (size_t)2048 * 512 * 2;    // 2 MB
  unsigned short* Whp  = (unsigned short*)ws; ws += (size_t)2048 * 512 * 2;    // 2 MB
  int*            pairs = (int*)ws;           ws += (size_t)32768 * 4;         // 128 KB
  int*            lmeta = (int*)ws;           ws += 256 * 4;
  int*            mrows = (int*)ws;           ws += 4096 * 4;
  unsigned long long* flag8 = (unsigned long long*)ws; ws += (size_t)32768 * 8; // 256 KB
  int*            tick  = (int*)ws;           ws += 64 * 4;

  prep<<<1793, 256, 0, stream>>>(Wi_x, Wf_x, Wo_x, Wu_x,
                                 Wi_h, Wf_h, Wo_h, Wu_h,
                                 Wxbf, Whp, (int*)flag8, tick);

  xprojL<<<4097, 512, 0, stream>>>(X, Wxbf, bi_x, bi_h, bf_x, bf_h, Xpre,
                                   parents, pairs, lmeta, mrows);

  treelstm_flag<<<512, 512, 0, stream>>>(Xpre, Whp, parents, pairs, lmeta,
                                         mrows, flag8, tick, Hout, Cbuf, Hbf);
}

// Round 17
// 491.052 us; speedup vs baseline: 1.0267x; 1.0267x over previous
//
#include <hip/hip_runtime.h>
#include <hip/hip_bf16.h>

static constexpr int LL = 256;   // sequence length / nodes
static constexpr int BB = 128;   // batch
static constexpr int HHH = 512;  // hidden dim

typedef __attribute__((ext_vector_type(8))) short bf16x8;
typedef __attribute__((ext_vector_type(4))) float f32x4;
typedef __attribute__((ext_vector_type(8))) unsigned short u16x8;
typedef __attribute__((ext_vector_type(4))) unsigned short u16x4;

__device__ __forceinline__ unsigned short f2bf(float f) {
  union { float f; unsigned u; } v; v.f = f;
  unsigned r = (v.u + 0x7FFFu + ((v.u >> 16) & 1u)) >> 16;
  return (unsigned short)r;
}
__device__ __forceinline__ float bf2f(unsigned short s) {
  union { unsigned u; float f; } v; v.u = ((unsigned)s) << 16;
  return v.f;
}
__device__ __forceinline__ float sigm(float x) { return 1.0f / (1.0f + __expf(-x)); }
__device__ __forceinline__ float tanh_f(float x) { return 1.0f - 2.0f / (__expf(2.0f * x) + 1.0f); }

// ---------------------------------------------------------------------------
// Kernel 1: prep — ONLY what xprojL depends on: cast the 4 x-weight
// matrices -> Wxbf.  (whpack + flag8/tick zeroing moved into the xprojL
// dispatch as tail blocks; they feed only the third dispatch.)
// ---------------------------------------------------------------------------
__global__ __launch_bounds__(256) void prep(
    const float* __restrict__ s0, const float* __restrict__ s1,
    const float* __restrict__ s2, const float* __restrict__ s3,
    unsigned short* __restrict__ wx) {
  int gid = blockIdx.x * 256 + threadIdx.x;
  int e = gid * 4;
  int m = e >> 18;
  int off = e & 0x3FFFF;
  const float* srcs[4] = {s0, s1, s2, s3};
  float4 v = *(const float4*)(srcs[m] + off);
  u16x4 o;
  o[0] = f2bf(v.x); o[1] = f2bf(v.y); o[2] = f2bf(v.z); o[3] = f2bf(v.w);
  *(u16x4*)(wx + (size_t)m * 262144 + off) = o;
}

// ---------------------------------------------------------------------------
// Kernel 2: xproj + levels + whpack + flag-zero (concurrent block roles).
//   block 0        : level assignment + bucketing + tile list.
//   blocks 1..4096 : one 128x128 tile of Xpre = cvt_bf16(X) @ Wx^T + bias
//                    (round-15 verbatim: 256 thr, T1 XCD-chunked swizzle,
//                    f32-direct A + reg-cvt swizzled ds_write, B via
//                    global_load_lds w16, LDS-staged coalesced epilogue).
//   blocks 4097..4608: pack 4 h-weight matrices -> Whp (hidden under GEMM).
//   blocks 4609..4865: zero flag8 (+tick in 4609).
// whpack/zero outputs are consumed only by the next dispatch -> no hazard.
// ---------------------------------------------------------------------------
__global__ __launch_bounds__(256) void xprojL(
    const float* __restrict__ X, const unsigned short* __restrict__ Wx,
    const float* __restrict__ bi_x, const float* __restrict__ bi_h,
    const float* __restrict__ bf_x, const float* __restrict__ bf_h,
    unsigned short* __restrict__ Xpre,
    const int* __restrict__ parents, int* __restrict__ pairs,
    int* __restrict__ lmeta, int* __restrict__ mrows,
    const float* __restrict__ h0, const float* __restrict__ h1,
    const float* __restrict__ h2, const float* __restrict__ h3,
    unsigned short* __restrict__ whp,
    int* __restrict__ flag8i, int* __restrict__ tick) {
  __shared__ union {
    unsigned short sh[2][8192];                 // 32 KB GEMM staging
    struct {
      unsigned short cnt2[128][130];            // 33.3 KB
      int off[130];
      int maxl;
    } lv;
  } U;
  const int tid = threadIdx.x;
  const int blk = blockIdx.x;

  if (blk >= 4097) {
    if (blk < 4609) {
      // ---- whpack role ----
      int gid = (blk - 4097) * 256 + tid;
      int lane = gid & 63;
      int kb   = (gid >> 6) & 15;
      int n16  = (gid >> 10) & 31;
      int g    = gid >> 15;
      const float* W = (g == 0) ? h0 : (g == 1) ? h1 : (g == 2) ? h2 : h3;
      int row = n16 * 16 + (lane & 15);
      int col = kb * 32 + (lane >> 4) * 8;
      const float4* s = (const float4*)(W + (size_t)row * 512 + col);
      float4 v0 = s[0], v1 = s[1];
      u16x8 o;
      o[0] = f2bf(v0.x); o[1] = f2bf(v0.y); o[2] = f2bf(v0.z); o[3] = f2bf(v0.w);
      o[4] = f2bf(v1.x); o[5] = f2bf(v1.y); o[6] = f2bf(v1.z); o[7] = f2bf(v1.w);
      *(u16x8*)&whp[(size_t)gid * 8] = o;
    } else {
      // ---- zero flag8 + tick ----
      int i = (blk - 4609) * 256 + tid;
      if (i < 65536) flag8i[i] = 0;
      if (blk == 4609 && tid < 9) tick[tid] = 0;
    }
    return;
  }

  if (blk == 0) {
    // ---- levels role (threads 0..127 carry state) ----
    const int b = tid;
    unsigned char mylvl[256];
    if (b < 128) {
      for (int l = 0; l < 130; ++l) U.lv.cnt2[b][l] = 0;
    }
    if (b == 0) U.lv.maxl = 0;
    __syncthreads();
    if (b < 128) {
      int maxl = 0;
      for (int t = 0; t < 256; ++t) {
        int p = parents[t * 128 + b];
        int l = (p < 0) ? 0 : (mylvl[p] + 1);
        if (l > 127) l = 127;
        mylvl[t] = (unsigned char)l;
        maxl = l > maxl ? l : maxl;
        U.lv.cnt2[b][l]++;
      }
      atomicMax(&U.lv.maxl, maxl);
    }
    __syncthreads();
    const int nlev = U.lv.maxl + 1;
    if (b < 128) {
      int l = b;
      int s = 0;
      if (l < nlev) for (int bb = 0; bb < 128; ++bb) s += U.lv.cnt2[bb][l];
      U.lv.off[l + 1] = s;
    }
    __syncthreads();
    if (b == 0) {
      U.lv.off[0] = 0;
      for (int l = 0; l < 128; ++l) U.lv.off[l + 1] += U.lv.off[l];
    }
    __syncthreads();
    if (b < 128) {
      int l = b;
      if (l < nlev) {
        int run = U.lv.off[l];
        for (int bb = 0; bb < 128; ++bb) {
          int c = U.lv.cnt2[bb][l];
          U.lv.cnt2[bb][l] = (unsigned short)run;
          run += c;
        }
      }
    }
    __syncthreads();
    if (b < 128) {
      for (int t = 0; t < 256; ++t) {
        int l = mylvl[t];
        int pos = U.lv.cnt2[b][l]++;
        pairs[pos] = t * 128 + b;
      }
    }
    if (b == 0) {
      int midx = 0;
      for (int l = 0; l < nlev; ++l) {
        int s = U.lv.off[l], e = U.lv.off[l + 1];
        for (int rb = s; rb < e; rb += 32) {
          int rc = (e - rb < 32) ? (e - rb) : 32;
          mrows[midx++] = (rb << 6) | rc;
        }
      }
      lmeta[0] = midx;
    }
    return;
  }

  // ---- xproj role (round-15 verbatim) ----
  const int d = blk - 1;                        // dispatch index 0..4095
  const int xblk = (d & 7) * 512 + (d >> 3);    // XCD-chunked swizzle (T1)
  const int m0 = (xblk >> 4) * 128;
  const int n0 = (xblk & 15) * 128;
  const int lane = tid & 63, w = tid >> 6;
  const int wr = w >> 1, wc = w & 1;
  const int hi = lane >> 4, l15 = lane & 15;
  f32x4 acc[4][4] = {};
  for (int kt = 0; kt < 8; ++kt) {
    const int k0 = kt * 64;
    __syncthreads();
#pragma unroll
    for (int i = 0; i < 4; ++i) {
      const int grp = i * 4 + w;               // 0..15
      const int unit = grp * 64 + lane;        // 0..1023
      const int row = unit >> 3, c8p = unit & 7;
      const int c8l = c8p ^ (row & 7);
      const unsigned short* gb = Wx + (size_t)(n0 + row) * 512 + k0 + c8l * 8;
      __builtin_amdgcn_global_load_lds(
          (const __attribute__((address_space(1))) unsigned int*)gb,
          (__attribute__((address_space(3))) unsigned int*)(&U.sh[1][grp * 512]),
          16, 0, 0);
    }
#pragma unroll
    for (int i = 0; i < 4; ++i) {
      const int unit = i * 256 + tid;          // 0..1023
      const int row = unit >> 3, c8l = unit & 7;
      const float* src = X + (size_t)(m0 + row) * 512 + k0 + c8l * 8;
      float4 v0 = ((const float4*)src)[0];
      float4 v1 = ((const float4*)src)[1];
      u16x8 o;
      o[0] = f2bf(v0.x); o[1] = f2bf(v0.y); o[2] = f2bf(v0.z); o[3] = f2bf(v0.w);
      o[4] = f2bf(v1.x); o[5] = f2bf(v1.y); o[6] = f2bf(v1.z); o[7] = f2bf(v1.w);
      *(u16x8*)&U.sh[0][row * 64 + ((c8l ^ (row & 7)) << 3)] = o;
    }
    __syncthreads();
#pragma unroll
    for (int kk = 0; kk < 2; ++kk) {
      const int kofs = kk * 32 + hi * 8;
      bf16x8 a[4], bb[4];
#pragma unroll
      for (int mi = 0; mi < 4; ++mi) {
        const int row = wr * 64 + mi * 16 + l15;
        a[mi] = *(const bf16x8*)&U.sh[0][row * 64 + (kofs ^ ((row & 7) << 3))];
      }
#pragma unroll
      for (int ni = 0; ni < 4; ++ni) {
        const int row = wc * 64 + ni * 16 + l15;
        bb[ni] = *(const bf16x8*)&U.sh[1][row * 64 + (kofs ^ ((row & 7) << 3))];
      }
#pragma unroll
      for (int mi = 0; mi < 4; ++mi)
#pragma unroll
        for (int ni = 0; ni < 4; ++ni)
          acc[mi][ni] = __builtin_amdgcn_mfma_f32_16x16x32_bf16(a[mi], bb[ni], acc[mi][ni], 0, 0, 0);
    }
  }
  // ---- epilogue: stage C in LDS, then coalesced writes ----
  __syncthreads();
  unsigned short* Cs = &U.sh[0][0];   // 128x128 u16 = 32 KB contiguous
#pragma unroll
  for (int ni = 0; ni < 4; ++ni) {
    const int coll = wc * 64 + ni * 16 + l15;
    const int gcol = n0 + coll;
    const int g = gcol >> 9, hh = gcol & 511;
    float badd = 0.0f;
    if (g == 0) badd = bi_x[hh] + bi_h[hh];
    else if (g == 1) badd = bf_x[hh] + bf_h[hh];
#pragma unroll
    for (int mi = 0; mi < 4; ++mi) {
      const int rbase = wr * 64 + mi * 16 + hi * 4;
#pragma unroll
      for (int q = 0; q < 4; ++q)
        Cs[(rbase + q) * 128 + coll] = f2bf(acc[mi][ni][q] + badd);
    }
  }
  __syncthreads();
#pragma unroll
  for (int u = 0; u < 8; ++u) {
    const int unit = u * 256 + tid;            // 0..2047
    const int row = unit >> 4, c8 = unit & 15;
    *(u16x8*)&Xpre[(size_t)(m0 + row) * 2048 + n0 + c8 * 8] =
        *(const u16x8*)&Cs[row * 128 + c8 * 8];
  }
}

// ---------------------------------------------------------------------------
// Kernel 3: recurrence — round-15 verbatim (flag8 vector release, round-10
// core: VGPR 100 / AGPR-resident weights, per-ct ticket queues, fence-free
// LLC protocol).  Stable at ~275 us across rounds 13-16 (structural floor).
// ---------------------------------------------------------------------------
__global__ __launch_bounds__(512, 2) void treelstm_flag(
    const unsigned short* __restrict__ Xpre,  // [L*B][2048]
    const unsigned short* __restrict__ Whp,   // packed [4][32][16][512]
    const int* __restrict__ parents,          // [L][B]
    const int* __restrict__ pairs,            // [32768] node ids by level
    const int* __restrict__ lmeta,            // [0] = mcnt
    const int* __restrict__ mrows,            // tile list (rbase<<6 | rcnt)
    unsigned long long* __restrict__ flag8,   // [32768] per-node ct bytes
    int* __restrict__ tick,                   // [8] ticket counters
    float* __restrict__ Hout,                 // [B][L][H]  (d_out)
    float* __restrict__ Cbuf,                 // [B][L][H]
    unsigned short* __restrict__ Hbf) {       // [B][L][H] bf16
  __shared__ unsigned short phs[32][536];     // 34.3KB
  __shared__ float gbuf[4][32][66];           // 33.8KB
  __shared__ int sh_ticket;
  const int tid = threadIdx.x;
  const int lane = tid & 63, w = tid >> 6;
  const int g = w & 3, nh = w >> 2;
  const int ct = blockIdx.x & 7;
  const int mcnt = lmeta[0];
  const int hi = lane >> 4, l15 = lane & 15;
  const unsigned long long FULL = 0x0101010101010101ull;

  // ---- preload weights for (gate g, cols ct*64+nh*32 ..+32) into regs ----
  bf16x8 wfrag[2][16];
  {
    const size_t base = (size_t)((g * 32 + ct * 4 + nh * 2) * 16) * 512 + lane * 8;
#pragma unroll
    for (int kb = 0; kb < 16; ++kb) {
      wfrag[0][kb] = *(const bf16x8*)&Whp[base + (size_t)kb * 512];
      wfrag[1][kb] = *(const bf16x8*)&Whp[base + (size_t)(16 + kb) * 512];
    }
  }
  // keep-alive: opaque values -> no rematerialization (AGPR residency).
#pragma unroll
  for (int kb = 0; kb < 16; ++kb) {
    asm volatile("" : "+v"(wfrag[0][kb]));
    asm volatile("" : "+v"(wfrag[1][kb]));
  }

  while (true) {
    __syncthreads();   // protect sh_ticket / phs / gbuf from previous iter
    if (tid == 0) sh_ticket = atomicAdd(&tick[ct], 1);
    __syncthreads();
    const int my = sh_ticket;
    if (my >= mcnt) break;
    const int mr = mrows[my];
    const int rbase = mr >> 6;
    const int rcnt = mr & 63;

    // thread -> (row r = tid>>4, chunk q16 = tid&15)
    const int r = tid >> 4;
    const int q16 = tid & 15;
    const int hc = q16 * 4;
    const int h = ct * 64 + hc;
    int node = 0, p = -1, b = 0;
    if (r < rcnt) {
      node = pairs[rbase + r];
      p = parents[node];
      b = node & 127;
    }
    // prefetch Xpre gate pre-activations (no dependency on parents)
    u16x4 xga[4] = {};
    if (r < rcnt) {
#pragma unroll
      for (int gg = 0; gg < 4; ++gg)
        xga[gg] = *(const u16x4*)(Xpre + (size_t)node * 2048 + gg * 512 + h);
    }

    // ---- phase A: wave-0 lanes poll readiness (relaxed u64 loads) ----
    if (tid < 32) {
      int pn = -1;
      if (tid < rcnt) {
        const int node2 = pairs[rbase + tid];
        const int p2 = parents[node2];
        if (p2 >= 0) pn = p2 * 128 + (node2 & 127);
      }
      if (pn >= 0) {
        while (__hip_atomic_load(&flag8[pn], __ATOMIC_RELAXED,
                                 __HIP_MEMORY_SCOPE_AGENT) != FULL)
          __builtin_amdgcn_s_sleep(1);
      }
    }
    __syncthreads();

    // ---- phase B: prefetch parent c; gather parent h rows into LDS ----
    float4 pc = make_float4(0.f, 0.f, 0.f, 0.f);
    if (r < rcnt && p >= 0)
      pc = *(const float4*)(Cbuf + ((size_t)b * LL + p) * HHH + h);
    if (p >= 0) {
      const unsigned short* src = Hbf + ((size_t)b * LL + p) * HHH + q16 * 32;
#pragma unroll
      for (int j = 0; j < 4; ++j)
        *(u16x8*)&phs[r][q16 * 32 + j * 8] = ((const u16x8*)src)[j];
    } else {
      u16x8 z = {};
#pragma unroll
      for (int j = 0; j < 4; ++j) *(u16x8*)&phs[r][q16 * 32 + j * 8] = z;
    }
    __syncthreads();

    // ---- phase C: wave (g, nh): 32 rows x 32 cols, K=512 ----
    f32x4 acc[2][2] = {};
#pragma unroll
    for (int kb = 0; kb < 16; ++kb) {
      const int ko = kb * 32 + 8 * hi;
      bf16x8 a0 = *(const bf16x8*)&phs[l15][ko];
      bf16x8 a1 = *(const bf16x8*)&phs[16 + l15][ko];
      acc[0][0] = __builtin_amdgcn_mfma_f32_16x16x32_bf16(a0, wfrag[0][kb], acc[0][0], 0, 0, 0);
      acc[1][0] = __builtin_amdgcn_mfma_f32_16x16x32_bf16(a1, wfrag[0][kb], acc[1][0], 0, 0, 0);
      acc[0][1] = __builtin_amdgcn_mfma_f32_16x16x32_bf16(a0, wfrag[1][kb], acc[0][1], 0, 0, 0);
      acc[1][1] = __builtin_amdgcn_mfma_f32_16x16x32_bf16(a1, wfrag[1][kb], acc[1][1], 0, 0, 0);
    }
#pragma unroll
    for (int mi = 0; mi < 2; ++mi)
#pragma unroll
      for (int ni = 0; ni < 2; ++ni)
#pragma unroll
        for (int qq = 0; qq < 4; ++qq)
          gbuf[g][mi * 16 + hi * 4 + qq][nh * 32 + ni * 16 + l15] = acc[mi][ni][qq];
    __syncthreads();

    // ---- phase D: elementwise gates ----
    float hva[4];
    size_t obase = 0;
    const bool valid = (r < rcnt);
    if (valid) {
      const int t = node >> 7;
      float xg[4][4];
#pragma unroll
      for (int gg = 0; gg < 4; ++gg)
#pragma unroll
        for (int j = 0; j < 4; ++j) xg[gg][j] = bf2f(xga[gg][j]);
      const float pcv[4] = {pc.x, pc.y, pc.z, pc.w};
      float cva[4];
#pragma unroll
      for (int j = 0; j < 4; ++j) {
        float iv = sigm(gbuf[0][r][hc + j] + xg[0][j]);
        float fv = sigm(gbuf[1][r][hc + j] + xg[1][j]);
        float ov = sigm(gbuf[2][r][hc + j] + xg[2][j]);
        float uv = tanh_f(gbuf[3][r][hc + j] + xg[3][j]);
        float cv = iv * uv + fv * pcv[j];
        cva[j] = cv;
        hva[j] = ov * tanh_f(cv);
      }
      obase = ((size_t)b * LL + t) * HHH + h;
      // Cbuf, Hbf: consumed by other WGs -> write through to LLC (sc1)
      union { float f[4]; unsigned long long u[2]; } cvu;
      cvu.f[0] = cva[0]; cvu.f[1] = cva[1]; cvu.f[2] = cva[2]; cvu.f[3] = cva[3];
      unsigned long long* cp = (unsigned long long*)(Cbuf + obase);
      __hip_atomic_store(cp, cvu.u[0], __ATOMIC_RELAXED, __HIP_MEMORY_SCOPE_AGENT);
      __hip_atomic_store(cp + 1, cvu.u[1], __ATOMIC_RELAXED, __HIP_MEMORY_SCOPE_AGENT);
      union { unsigned short s[4]; unsigned long long u; } hbu;
      hbu.s[0] = f2bf(hva[0]); hbu.s[1] = f2bf(hva[1]);
      hbu.s[2] = f2bf(hva[2]); hbu.s[3] = f2bf(hva[3]);
      __hip_atomic_store((unsigned long long*)(Hbf + obase), hbu.u,
                         __ATOMIC_RELAXED, __HIP_MEMORY_SCOPE_AGENT);
    }
    // drain this wave's LLC stores (row's 16 threads all in this wave)
    asm volatile("s_waitcnt vmcnt(0)" ::: "memory");
    if (valid && q16 == 0) {
      unsigned char* fb = (unsigned char*)flag8 + ((size_t)node * 8 + ct);
      __hip_atomic_store(fb, (unsigned char)1, __ATOMIC_RELAXED,
                         __HIP_MEMORY_SCOPE_AGENT);
    }
    // Hout (pure output, HBM) after the release -> off the critical path
    if (valid)
      *(float4*)(Hout + obase) = make_float4(hva[0], hva[1], hva[2], hva[3]);
  }
}

// ---------------------------------------------------------------------------
extern "C" void kernel_launch(void* const* d_in, const int* in_sizes, int n_in,
                              void* d_out, int out_size, void* d_ws, size_t ws_size,
                              hipStream_t stream) {
  const float* X    = (const float*)d_in[0];
  const float* Wi_x = (const float*)d_in[1];
  const float* bi_x = (const float*)d_in[2];
  const float* Wi_h = (const float*)d_in[3];
  const float* bi_h = (const float*)d_in[4];
  const float* Wf_x = (const float*)d_in[5];
  const float* bf_x = (const float*)d_in[6];
  const float* Wf_h = (const float*)d_in[7];
  const float* bf_h = (const float*)d_in[8];
  const float* Wo_x = (const float*)d_in[9];
  const float* Wo_h = (const float*)d_in[10];
  const float* Wu_x = (const float*)d_in[11];
  const float* Wu_h = (const float*)d_in[12];
  const int* parents = (const int*)d_in[13];
  float* Hout = (float*)d_out;

  char* ws = (char*)d_ws;
  unsigned short* Xpre = (unsigned short*)ws; ws += (size_t)32768 * 2048 * 2;  // 128 MB
  unsigned short* Hbf  = (unsigned short*)ws; ws += (size_t)BB * LL * HHH * 2; // 32 MB
  float*          Cbuf = (float*)ws;          ws += (size_t)BB * LL * HHH * 4; // 64 MB
  unsigned short* Wxbf = (unsigned short*)ws; ws += (size_t)2048 * 512 * 2;    // 2 MB
  unsigned short* Whp  = (unsigned short*)ws; ws += (size_t)2048 * 512 * 2;    // 2 MB
  int*            pairs = (int*)ws;           ws += (size_t)32768 * 4;         // 128 KB
  int*            lmeta = (int*)ws;           ws += 256 * 4;
  int*            mrows = (int*)ws;           ws += 4096 * 4;
  unsigned long long* flag8 = (unsigned long long*)ws; ws += (size_t)32768 * 8; // 256 KB
  int*            tick  = (int*)ws;           ws += 64 * 4;

  prep<<<1024, 256, 0, stream>>>(Wi_x, Wf_x, Wo_x, Wu_x, Wxbf);

  xprojL<<<4866, 256, 0, stream>>>(X, Wxbf, bi_x, bi_h, bf_x, bf_h, Xpre,
                                   parents, pairs, lmeta, mrows,
                                   Wi_h, Wf_h, Wo_h, Wu_h, Whp,
                                   (int*)flag8, tick);

  treelstm_flag<<<512, 512, 0, stream>>>(Xpre, Whp, parents, pairs, lmeta,
                                         mrows, flag8, tick, Hout, Cbuf, Hbf);
}